// Round 1
// baseline (43257.761 us; speedup 1.0000x reference)
//
#include <hip/hip_runtime.h>
#include <math.h>

// Problem constants
//   N=2048 nodes, E=1024 edges, F=512 hidden, C=40 classes, 10 layers
//   out: [81920 log_probs][10 energies][10 energies_exp][10 snorms][1 gap]

// ---------------------------------------------------------------------------
// Generic tiled f32 GEMM: C = alpha*op(A)*op(B) (+ beta*C, optional relu)
// Row-major. TA: a(m,k)=A[k*lda+m]; TB: b(k,n)=B[n*ldb+k].
// gridDim.z = S (split-K). S==1: direct epilogue. S>1: partials into Cpart,
// summed by reduce_parts (which applies beta/relu).
// NOTE: no __restrict__ on A/B/C — some calls run in-place (C aliases A).
// ---------------------------------------------------------------------------
template<bool TA, bool TB>
__global__ __launch_bounds__(256)
void gemm_f32(const float* A, int lda, const float* B, int ldb,
              float* C, int ldc, float* Cpart,
              int M, int N, int K, float alpha, float beta, int relu)
{
    const int S = (int)gridDim.z, z = (int)blockIdx.z;
    const int kchunk = (K + S - 1) / S;
    const int k0 = z * kchunk;
    const int k1 = (K < k0 + kchunk) ? K : (k0 + kchunk);
    const int bm = blockIdx.y * 64, bn = blockIdx.x * 64;
    __shared__ float As[16][68];
    __shared__ float Bs[16][68];
    const int tid = threadIdx.x;
    const int tx = tid & 15, ty = tid >> 4;
    float acc[4][4] = {};
    for (int kk = k0; kk < k1; kk += 16) {
        for (int i = tid; i < 1024; i += 256) {
            int m, k;
            if (TA) { m = i & 63; k = i >> 6; } else { k = i & 15; m = i >> 4; }
            int gm = bm + m, gk = kk + k;
            float v = 0.f;
            if (gm < M && gk < k1) v = TA ? A[(size_t)gk*lda + gm] : A[(size_t)gm*lda + gk];
            As[k][m] = v;
        }
        for (int i = tid; i < 1024; i += 256) {
            int n, k;
            if (TB) { k = i & 15; n = i >> 4; } else { n = i & 63; k = i >> 6; }
            int gn = bn + n, gk = kk + k;
            float v = 0.f;
            if (gn < N && gk < k1) v = TB ? B[(size_t)gn*ldb + gk] : B[(size_t)gk*ldb + gn];
            Bs[k][n] = v;
        }
        __syncthreads();
        #pragma unroll
        for (int k = 0; k < 16; ++k) {
            float4 ra4 = *reinterpret_cast<const float4*>(&As[k][ty*4]);
            float4 rb4 = *reinterpret_cast<const float4*>(&Bs[k][tx*4]);
            float ra[4] = {ra4.x, ra4.y, ra4.z, ra4.w};
            float rb[4] = {rb4.x, rb4.y, rb4.z, rb4.w};
            #pragma unroll
            for (int i = 0; i < 4; ++i)
                #pragma unroll
                for (int j = 0; j < 4; ++j)
                    acc[i][j] += ra[i] * rb[j];
        }
        __syncthreads();
    }
    if (S == 1) {
        #pragma unroll
        for (int i = 0; i < 4; ++i) {
            int gm = bm + ty*4 + i;
            if (gm >= M) continue;
            #pragma unroll
            for (int j = 0; j < 4; ++j) {
                int gn = bn + tx*4 + j;
                if (gn >= N) continue;
                float v = alpha * acc[i][j];
                if (beta != 0.f) v += beta * C[(size_t)gm*ldc + gn];
                if (relu) v = fmaxf(v, 0.f);
                C[(size_t)gm*ldc + gn] = v;
            }
        }
    } else {
        float* P = Cpart + (size_t)z * M * N;
        #pragma unroll
        for (int i = 0; i < 4; ++i) {
            int gm = bm + ty*4 + i;
            if (gm >= M) continue;
            #pragma unroll
            for (int j = 0; j < 4; ++j) {
                int gn = bn + tx*4 + j;
                if (gn >= N) continue;
                P[(size_t)gm*N + gn] = alpha * acc[i][j];
            }
        }
    }
}

__global__ void reduce_parts(const float* Cpart, float* C, int M, int N, int ldc,
                             int S, float beta, int relu)
{
    int total = M * N;
    for (int idx = blockIdx.x*256 + threadIdx.x; idx < total; idx += gridDim.x*256) {
        float s = 0.f;
        for (int z = 0; z < S; ++z) s += Cpart[(size_t)z*total + idx];
        int mm = idx / N, nn = idx % N;
        float v = s;
        if (beta != 0.f) v += beta * C[(size_t)mm*ldc + nn];
        if (relu) v = fmaxf(v, 0.f);
        C[(size_t)mm*ldc + nn] = v;
    }
}

// ---------------------------------------------------------------------------
// Small utility kernels
// ---------------------------------------------------------------------------
__global__ void row_deg(const float* H, float* dv) {
    int row = blockIdx.x*4 + (threadIdx.x >> 6);
    int lane = threadIdx.x & 63;
    if (row >= 2048) return;
    float s = 0.f;
    for (int e = lane; e < 1024; e += 64) s += H[(size_t)row*1024 + e];
    for (int o = 32; o; o >>= 1) s += __shfl_down(s, o, 64);
    if (lane == 0) dv[row] = s;
}
__global__ void col_deg_part(const float* H, float* colpart) {
    int e = blockIdx.x*256 + threadIdx.x;   // gridDim.x = 4
    int z = blockIdx.y;                     // 8 chunks over nodes
    float s = 0.f;
    for (int n = z*256; n < z*256 + 256; ++n) s += H[(size_t)n*1024 + e];
    colpart[(size_t)z*1024 + e] = s;
}
__global__ void col_deg_fin(const float* colpart, float* de) {
    int e = blockIdx.x*256 + threadIdx.x;
    float s = 0.f;
    for (int z = 0; z < 8; ++z) s += colpart[(size_t)z*1024 + e];
    de[e] = s;
}

__global__ void dot_partial(const float* a, const float* b, int n, float* partials) {
    __shared__ float red[256];
    int tid = threadIdx.x;
    float s = 0.f;
    for (int i = blockIdx.x*256 + tid; i < n; i += gridDim.x*256) s += a[i]*b[i];
    red[tid] = s; __syncthreads();
    for (int st = 128; st; st >>= 1) { if (tid < st) red[tid] += red[tid+st]; __syncthreads(); }
    if (tid == 0) partials[blockIdx.x] = red[0];
}
__global__ void finalize_sum(const float* partials, int n, float* outp) {
    __shared__ float red[256];
    int tid = threadIdx.x;
    red[tid] = (tid < n) ? partials[tid] : 0.f;
    __syncthreads();
    for (int st = 128; st; st >>= 1) { if (tid < st) red[tid] += red[tid+st]; __syncthreads(); }
    if (tid == 0) *outp = red[0];
}

// y = h / sqrt(dv+eps); srow = rowwise sum(y^2)
__global__ void yscale(const float* h, int F, const float* dv, float* y, float* srow) {
    int row = blockIdx.x*4 + (threadIdx.x >> 6);
    int lane = threadIdx.x & 63;
    if (row >= 2048) return;
    float rs = 1.0f / sqrtf(dv[row] + 1e-10f);
    float ss = 0.f;
    for (int f = lane; f < F; f += 64) {
        float t = h[(size_t)row*F + f] * rs;
        y[(size_t)row*F + f] = t;
        ss += t*t;
    }
    for (int o = 32; o; o >>= 1) ss += __shfl_down(ss, o, 64);
    if (lane == 0) srow[row] = ss;
}

// per-edge: (d_e*q_e - ||m_e||^2)/(d_e+eps), block-partial sums
__global__ void edge_energy(const float* m, int F, const float* de, const float* q,
                            float* partials) {
    int wave = threadIdx.x >> 6, lane = threadIdx.x & 63;
    __shared__ float acc4[4];
    float acc = 0.f;
    for (int t = 0; t < 16; ++t) {
        int e = blockIdx.x*64 + wave*16 + t;
        float me2 = 0.f;
        for (int f = lane; f < F; f += 64) { float v = m[(size_t)e*F + f]; me2 += v*v; }
        for (int o = 32; o; o >>= 1) me2 += __shfl_down(me2, o, 64);
        if (lane == 0) acc += (de[e]*q[e] - me2) / (de[e] + 1e-10f);
    }
    if (lane == 0) acc4[wave] = acc;
    __syncthreads();
    if (threadIdx.x == 0) partials[blockIdx.x] = acc4[0]+acc4[1]+acc4[2]+acc4[3];
}

// log_softmax over axis=1 (the 2048 nodes), per class column
__global__ void logsoftmax(const float* xf, float* outp) {
    __shared__ float red[256];
    int c = blockIdx.x, tid = threadIdx.x;
    float mx = -3.0e38f;
    for (int n = tid; n < 2048; n += 256) mx = fmaxf(mx, xf[(size_t)n*40 + c]);
    red[tid] = mx; __syncthreads();
    for (int st = 128; st; st >>= 1) { if (tid < st) red[tid] = fmaxf(red[tid], red[tid+st]); __syncthreads(); }
    mx = red[0]; __syncthreads();
    float s = 0.f;
    for (int n = tid; n < 2048; n += 256) s += expf(xf[(size_t)n*40 + c] - mx);
    red[tid] = s; __syncthreads();
    for (int st = 128; st; st >>= 1) { if (tid < st) red[tid] += red[tid+st]; __syncthreads(); }
    float lse = mx + logf(red[0]);
    for (int n = tid; n < 2048; n += 256) outp[(size_t)n*40 + c] = xf[(size_t)n*40 + c] - lse;
}

// ---------------------------------------------------------------------------
// Block-Lanczos support
// ---------------------------------------------------------------------------
__global__ void init_q0(float* Q) {
    int idx = blockIdx.x*256 + threadIdx.x;
    if (idx < 2048*64) {
        int n = idx >> 6, c = idx & 63;
        Q[(size_t)n*2048 + c] = (n == c) ? 1.f : 0.f;
    }
}
__global__ void copy_ablock(const float* Creo, float* Ab, int s) {
    int idx = blockIdx.x*256 + threadIdx.x;
    if (idx < 4096) {
        int a = idx >> 6, b = idx & 63;
        Ab[(size_t)s*4096 + idx] = Creo[(size_t)(64*s + a)*64 + b];
    }
}

// Cholesky of 64x64 G (upper R), Rinv = R^{-1}. mode0: Bout=R. mode1: Bout = R*Bout_old.
__global__ __launch_bounds__(256)
void cholinv(const float* G, float* Rinv, float* Bout, int mode) {
    __shared__ float R[64][65];
    __shared__ float Xs[64][65];
    int tid = threadIdx.x;
    for (int idx = tid; idx < 4096; idx += 256) R[idx>>6][idx&63] = G[idx];
    __syncthreads();
    for (int k = 0; k < 64; ++k) {
        if (tid == 0) R[k][k] = sqrtf(fmaxf(R[k][k], 1e-20f));
        __syncthreads();
        float rkk = R[k][k];
        for (int j = k + 1 + tid; j < 64; j += 256) R[k][j] /= rkk;
        __syncthreads();
        for (int idx = tid; idx < 4096; idx += 256) {
            int i = idx>>6, j = idx&63;
            if (i > k && j >= i) R[i][j] -= R[k][i]*R[k][j];
        }
        __syncthreads();
    }
    for (int idx = tid; idx < 4096; idx += 256) Xs[idx>>6][idx&63] = 0.f;
    __syncthreads();
    if (tid < 64) {
        int j = tid;
        for (int i = j; i >= 0; --i) {
            float s = (i == j) ? 1.f : 0.f;
            for (int k2 = i + 1; k2 <= j; ++k2) s -= R[i][k2]*Xs[k2][j];
            Xs[i][j] = s / R[i][i];
        }
    }
    __syncthreads();
    for (int idx = tid; idx < 4096; idx += 256) Rinv[idx] = Xs[idx>>6][idx&63];
    __syncthreads();
    if (mode == 0) {
        for (int idx = tid; idx < 4096; idx += 256) {
            int i = idx>>6, j = idx&63;
            Bout[idx] = (j >= i) ? R[i][j] : 0.f;
        }
    } else {
        for (int idx = tid; idx < 4096; idx += 256) Xs[idx>>6][idx&63] = Bout[idx];
        __syncthreads();
        for (int idx = tid; idx < 4096; idx += 256) {
            int i = idx>>6, j = idx&63;
            float s = 0.f;
            if (j >= i) for (int k2 = i; k2 <= j; ++k2) s += R[i][k2]*Xs[k2][j];
            Bout[idx] = s;
        }
    }
}

// band[c*65+r] = T[c+r, c], r=0..64 (lower band, bandwidth 64)
__global__ void assemble_band(const float* Ab, const float* Bb, float* band) {
    int idx = blockIdx.x*256 + threadIdx.x;
    if (idx >= 2048*65) return;
    int c = idx / 65, r = idx % 65;
    int row = c + r;
    float v = 0.f;
    if (row < 2048) {
        int j = c >> 6, q = c & 63, rr = q + r;
        if (rr <= 63) {
            const float* A = Ab + (size_t)j*4096;
            v = 0.5f*(A[rr*64 + q] + A[q*64 + rr]);
        } else if (j < 31) {
            int p = rr - 64;
            v = Bb[(size_t)j*4096 + p*64 + q];
        }
    }
    band[idx] = v;
}

// Sturm count via band LDL^T in f64, one workgroup per shift.
__global__ __launch_bounds__(256)
void band_count(const float* band, const double* shifts, int* counts) {
    __shared__ double win[65][66];
    __shared__ double lvec[65];
    __shared__ int cnt;
    int tid = threadIdx.x;
    double sigma = shifts[blockIdx.x];
    if (tid == 0) cnt = 0;
    for (int idx = tid; idx < 65*65; idx += 256) {
        int c = idx / 65, r = idx % 65;
        win[c][r] = (double)band[c*65 + r] - (r == 0 ? sigma : 0.0);
    }
    __syncthreads();
    for (int c = 0; c < 2048; ++c) {
        int cs = c % 65;
        double d = win[cs][0];
        if (fabs(d) < 1e-100) d = (d < 0 ? -1e-100 : 1e-100);
        if (tid == 0 && d < 0) cnt++;
        if (tid >= 1 && tid <= 64) lvec[tid] = win[cs][tid] / d;
        __syncthreads();
        for (int idx = tid; idx < 4096; idx += 256) {
            int i = (idx >> 6) + 1, j = (idx & 63) + 1;
            if (j >= i) win[(cs + i) % 65][j - i] -= lvec[i] * win[cs][j];
        }
        __syncthreads();
        int cn = c + 65;
        if (cn < 2048) {
            for (int r = tid; r <= 64; r += 256)
                win[cs][r] = (double)band[cn*65 + r] - (r == 0 ? sigma : 0.0);
        }
        // next iteration's post-lvec barrier orders the load vs. the next update
    }
    __syncthreads();
    if (tid == 0) counts[blockIdx.x] = cnt;
}

// Bisection driver. mode0: init log-spaced shifts. mode1: bracket from round 1.
// mode2: refine. mode3: refine + write gap.
__global__ void bisect(double* shifts, const int* counts, double* st, float* gap_out, int mode) {
    if (threadIdx.x != 0) return;
    if (mode == 0) {
        shifts[0] = 1e-10;
        double l0 = log(1e-6), l1 = log(0.5);
        for (int i = 1; i < 64; ++i) shifts[i] = exp(l0 + (l1 - l0)*(i - 1)/62.0);
        return;
    }
    if (mode == 1) {
        int n0 = counts[0];
        double lo = shifts[63], hi = 1.5;
        for (int i = 1; i < 64; ++i) if (counts[i] > n0) { lo = shifts[i-1]; hi = shifts[i]; break; }
        st[0] = lo; st[1] = hi; st[2] = (double)n0;
        for (int i = 0; i < 64; ++i) shifts[i] = lo + (hi - lo)*(i + 1)/65.0;
        return;
    }
    int n0 = (int)st[2];
    double lo = st[0], hi = st[1];
    double nlo = shifts[63], nhi = hi;
    for (int i = 0; i < 64; ++i) if (counts[i] > n0) { nhi = shifts[i]; nlo = (i == 0) ? lo : shifts[i-1]; break; }
    st[0] = nlo; st[1] = nhi;
    if (mode == 3) *gap_out = (float)(0.5*(nlo + nhi));
    else for (int i = 0; i < 64; ++i) shifts[i] = nlo + (nhi - nlo)*(i + 1)/65.0;
}

// Lanczos (32 steps, no reorth) on Gram matrix -> sigma_max = sqrt(lambda_max)
__global__ __launch_bounds__(256)
void snorm_lanczos(const float* Gall, const float* G40, float* outp) {
    int w = blockIdx.x, tid = threadIdx.x;
    int n = (w < 9) ? 512 : 40;
    const float* G = (w < 9) ? (Gall + (size_t)w*512*512) : G40;
    __shared__ float v[512], vp[512], wv[512], red[256];
    __shared__ float al[32], be[32];
    float inv0 = 1.f / sqrtf((float)n);
    for (int i = tid; i < n; i += 256) { v[i] = inv0; vp[i] = 0.f; }
    __syncthreads();
    float beta_prev = 0.f;
    for (int s = 0; s < 32; ++s) {
        for (int r = tid; r < n; r += 256) {
            const float* row = G + (size_t)r*n;
            float sum = 0.f;
            for (int k2 = 0; k2 < n; ++k2) sum += row[k2]*v[k2];
            wv[r] = sum;
        }
        __syncthreads();
        float p = 0.f;
        for (int i = tid; i < n; i += 256) p += v[i]*wv[i];
        red[tid] = p; __syncthreads();
        for (int st = 128; st; st >>= 1) { if (tid < st) red[tid] += red[tid+st]; __syncthreads(); }
        float alpha = red[0]; __syncthreads();
        for (int i = tid; i < n; i += 256) wv[i] -= alpha*v[i] + beta_prev*vp[i];
        __syncthreads();
        p = 0.f;
        for (int i = tid; i < n; i += 256) p += wv[i]*wv[i];
        red[tid] = p; __syncthreads();
        for (int st = 128; st; st >>= 1) { if (tid < st) red[tid] += red[tid+st]; __syncthreads(); }
        float beta = sqrtf(fmaxf(red[0], 0.f)); __syncthreads();
        if (tid == 0) { al[s] = alpha; be[s] = beta; }
        float ib = 1.f / fmaxf(beta, 1e-20f);
        for (int i = tid; i < n; i += 256) { float t = v[i]; vp[i] = t; v[i] = wv[i]*ib; }
        beta_prev = beta;
        __syncthreads();
    }
    if (tid == 0) {
        float hi = 0.f;
        for (int s = 0; s < 32; ++s) {
            float g2 = al[s] + be[s] + (s ? be[s-1] : 0.f);
            hi = fmaxf(hi, g2);
        }
        float lo = 0.f;
        for (int it = 0; it < 48; ++it) {
            float mid = 0.5f*(lo + hi);
            float d = al[0] - mid; int c2 = (d < 0.f);
            for (int s = 1; s < 32; ++s) {
                float dp = d;
                if (fabsf(dp) < 1e-25f) dp = (dp < 0.f) ? -1e-25f : 1e-25f;
                d = (al[s] - mid) - be[s-1]*be[s-1]/dp;
                c2 += (d < 0.f);
            }
            if (c2 == 32) hi = mid; else lo = mid;
        }
        outp[w] = sqrtf(fmaxf(0.5f*(lo + hi), 0.f));
    }
}

// ---------------------------------------------------------------------------
// Host driver
// ---------------------------------------------------------------------------
static void launch_gemm(hipStream_t st, int ta, int tb, int M, int N, int K,
                        const float* A, int lda, const float* B, int ldb,
                        float* C, int ldc, float alpha, float beta, int relu,
                        float* Cpart, int S)
{
    dim3 grid((unsigned)((N + 63)/64), (unsigned)((M + 63)/64), (unsigned)S);
    if (!ta && !tb)      gemm_f32<false,false><<<grid,256,0,st>>>(A,lda,B,ldb,C,ldc,Cpart,M,N,K,alpha,beta,relu);
    else if (!ta && tb)  gemm_f32<false,true ><<<grid,256,0,st>>>(A,lda,B,ldb,C,ldc,Cpart,M,N,K,alpha,beta,relu);
    else if (ta && !tb)  gemm_f32<true ,false><<<grid,256,0,st>>>(A,lda,B,ldb,C,ldc,Cpart,M,N,K,alpha,beta,relu);
    else                 gemm_f32<true ,true ><<<grid,256,0,st>>>(A,lda,B,ldb,C,ldc,Cpart,M,N,K,alpha,beta,relu);
    if (S > 1) {
        int total = M * N;
        int g = (total + 255)/256; if (g > 2048) g = 2048;
        reduce_parts<<<g,256,0,st>>>(Cpart, C, M, N, ldc, S, beta, relu);
    }
}

extern "C" void kernel_launch(void* const* d_in, const int* in_sizes, int n_in,
                              void* d_out, int out_size, void* d_ws, size_t ws_size,
                              hipStream_t stream)
{
    (void)in_sizes; (void)n_in; (void)out_size; (void)ws_size;
    const float* X  = (const float*)d_in[0];   // [1,2048,512]
    const float* Lm = (const float*)d_in[1];   // [1,2048,2048]
    const float* H  = (const float*)d_in[2];   // [2048,1024]
    const float* Wf = (const float*)d_in[3];   // [512,512]
    const float* Wm = (const float*)d_in[4];   // [8,512,512]
    const float* Wl = (const float*)d_in[5];   // [40,512]
    float* out = (float*)d_out;

    float* ws = (float*)d_ws;
    size_t off = 0;
    auto alloc = [&](size_t n) { float* p = ws + off; off += (n + 255) & ~(size_t)255; return p; };
    float* hA    = alloc((size_t)2048*512);
    float* hB    = alloc((size_t)2048*512);
    float* u     = alloc((size_t)2048*512);
    float* y     = alloc((size_t)2048*512);
    float* mE    = alloc((size_t)1024*512);
    float* Cpart = alloc((size_t)8*2048*64);      // split-K partials (max 1M floats)
    float* Qall  = alloc((size_t)2048*2048);      // Lanczos basis; reused for snorm Grams
    float* Z     = alloc((size_t)2048*64);
    float* Creo  = alloc((size_t)2048*64);
    float* G     = alloc(64*64);
    float* Rinv  = alloc(64*64);
    float* Ab    = alloc((size_t)32*64*64);
    float* Bb    = alloc((size_t)32*64*64);
    float* band  = alloc((size_t)2048*65);
    float* G40   = alloc(40*40);
    float* dv    = alloc(2048);
    float* de    = alloc(1024);
    float* srow  = alloc(2048);
    float* qE    = alloc(1024);
    float* partials = alloc(256);
    float* colpart  = alloc(8*1024);
    double* shifts  = (double*)alloc(128);
    double* bstate  = (double*)alloc(8);
    int* counts     = (int*)alloc(64);
    float* sG = Qall;  // reuse after band assembly

    // degrees
    row_deg<<<512,256,0,stream>>>(H, dv);
    col_deg_part<<<dim3(4,8),256,0,stream>>>(H, colpart);
    col_deg_fin<<<4,256,0,stream>>>(colpart, de);

    // u0 = L x
    launch_gemm(stream, 0,0, 2048,512,2048, Lm,2048, X,512, u,512, 1.f,0.f,0, Cpart,1);

    // 10 layers
    for (int k = 0; k < 10; ++k) {
        const int Fo = (k < 9) ? 512 : 40;
        const float* W = (k == 0) ? Wf : ((k < 9) ? (Wm + (size_t)(k-1)*512*512) : Wl);
        float* h = (k & 1) ? hB : hA;
        // h = relu(u W^T)
        launch_gemm(stream, 0,1, 2048,Fo,512, u,512, W,512, h,Fo, 1.f,0.f,1, Cpart,1);
        // u = L h   (serves energy AND next layer)
        launch_gemm(stream, 0,0, 2048,Fo,2048, Lm,2048, h,Fo, u,Fo, 1.f,0.f,0, Cpart,1);
        // energies[k] = <h, u>
        dot_partial<<<256,256,0,stream>>>(h, u, 2048*Fo, partials);
        finalize_sum<<<1,256,0,stream>>>(partials, 256, out + 81920 + k);
        // expanded energy
        yscale<<<512,256,0,stream>>>(h, Fo, dv, y, srow);
        launch_gemm(stream, 1,0, 1024,1,2048, H,1024, srow,1, qE,1, 1.f,0.f,0, Cpart,8);
        launch_gemm(stream, 1,0, 1024,Fo,2048, H,1024, y,Fo, mE,Fo, 1.f,0.f,0, Cpart,1);
        edge_energy<<<16,256,0,stream>>>(mE, Fo, de, qE, partials);
        finalize_sum<<<1,256,0,stream>>>(partials, 16, out + 81930 + k);
    }
    // log_softmax over nodes; final h lives in hB (k=9 odd)
    logsoftmax<<<40,256,0,stream>>>(hB, out);

    // ---- block Lanczos -> band-64 similar matrix ----
    init_q0<<<512,256,0,stream>>>(Qall);
    for (int s = 0; s < 32; ++s) {
        // Z = L * Q_s
        launch_gemm(stream, 0,0, 2048,64,2048, Lm,2048, Qall + 64*s,2048, Z,64, 1.f,0.f,0, Cpart,4);
        // Creo = Qall(:,0..64(s+1))^T * Z   (block s = A_s)
        launch_gemm(stream, 1,0, 64*(s+1),64,2048, Qall,2048, Z,64, Creo,64, 1.f,0.f,0, Cpart,8);
        copy_ablock<<<16,256,0,stream>>>(Creo, Ab, s);
        // Z -= Qall * Creo  (full one-pass reorthogonalization)
        launch_gemm(stream, 0,0, 2048,64,64*(s+1), Qall,2048, Creo,64, Z,64, -1.f,1.f,0, Cpart,2);
        if (s < 31) {
            // CholQR pass 1
            launch_gemm(stream, 1,0, 64,64,2048, Z,64, Z,64, G,64, 1.f,0.f,0, Cpart,16);
            cholinv<<<1,256,0,stream>>>(G, Rinv, Bb + (size_t)s*4096, 0);
            launch_gemm(stream, 0,0, 2048,64,64, Z,64, Rinv,64, Qall + 64*(s+1),2048, 1.f,0.f,0, Cpart,1);
            // CholQR pass 2 (in-place refresh of block s+1), B_s = R2*R1
            launch_gemm(stream, 1,0, 64,64,2048, Qall + 64*(s+1),2048, Qall + 64*(s+1),2048, G,64, 1.f,0.f,0, Cpart,16);
            cholinv<<<1,256,0,stream>>>(G, Rinv, Bb + (size_t)s*4096, 1);
            launch_gemm(stream, 0,0, 2048,64,64, Qall + 64*(s+1),2048, Rinv,64, Qall + 64*(s+1),2048, 1.f,0.f,0, Cpart,1);
        }
    }
    assemble_band<<<520,256,0,stream>>>(Ab, Bb, band);
    // inertia bisection for smallest eigenvalue > 1e-10
    bisect<<<1,64,0,stream>>>(shifts, counts, bstate, out + 81950, 0);
    for (int r = 1; r <= 3; ++r) {
        band_count<<<64,256,0,stream>>>(band, shifts, counts);
        bisect<<<1,64,0,stream>>>(shifts, counts, bstate, out + 81950, r);
    }

    // ---- spectral norms ----
    for (int i = 0; i < 9; ++i) {
        const float* W = (i == 0) ? Wf : (Wm + (size_t)(i-1)*512*512);
        launch_gemm(stream, 1,0, 512,512,512, W,512, W,512, sG + (size_t)i*512*512,512, 1.f,0.f,0, Cpart,1);
    }
    launch_gemm(stream, 0,1, 40,40,512, Wl,512, Wl,512, G40,40, 1.f,0.f,0, Cpart,1);
    snorm_lanczos<<<10,256,0,stream>>>(sG, G40, out + 81940);
}

// Round 2
// 35046.988 us; speedup vs baseline: 1.2343x; 1.2343x over previous
//
#include <hip/hip_runtime.h>
#include <math.h>

// Problem constants
//   N=2048 nodes, E=1024 edges, F=512 hidden, C=40 classes, 10 layers
//   out: [81920 log_probs][10 energies][10 energies_exp][10 snorms][1 gap]

// ---------------------------------------------------------------------------
// 64x64-tile f32 GEMM (fallback / small-N shapes). Row-major.
// TA: a(m,k)=A[k*lda+m]; TB: b(k,n)=B[n*ldb+k].
// gridDim.z = S (split-K). S==1: direct epilogue. S>1: partials into Cpart.
// ---------------------------------------------------------------------------
template<bool TA, bool TB>
__global__ __launch_bounds__(256)
void gemm_f32(const float* A, int lda, const float* B, int ldb,
              float* C, int ldc, float* Cpart,
              int M, int N, int K, float alpha, float beta, int relu)
{
    const int S = (int)gridDim.z, z = (int)blockIdx.z;
    const int kchunk = (K + S - 1) / S;
    const int k0 = z * kchunk;
    const int k1 = (K < k0 + kchunk) ? K : (k0 + kchunk);
    const int bm = blockIdx.y * 64, bn = blockIdx.x * 64;
    __shared__ float As[16][68];
    __shared__ float Bs[16][68];
    const int tid = threadIdx.x;
    const int tx = tid & 15, ty = tid >> 4;
    float acc[4][4] = {};
    for (int kk = k0; kk < k1; kk += 16) {
        for (int i = tid; i < 1024; i += 256) {
            int m, k;
            if (TA) { m = i & 63; k = i >> 6; } else { k = i & 15; m = i >> 4; }
            int gm = bm + m, gk = kk + k;
            float v = 0.f;
            if (gm < M && gk < k1) v = TA ? A[(size_t)gk*lda + gm] : A[(size_t)gm*lda + gk];
            As[k][m] = v;
        }
        for (int i = tid; i < 1024; i += 256) {
            int n, k;
            if (TB) { k = i & 15; n = i >> 4; } else { n = i & 63; k = i >> 6; }
            int gn = bn + n, gk = kk + k;
            float v = 0.f;
            if (gn < N && gk < k1) v = TB ? B[(size_t)gn*ldb + gk] : B[(size_t)gk*ldb + gn];
            Bs[k][n] = v;
        }
        __syncthreads();
        #pragma unroll
        for (int k = 0; k < 16; ++k) {
            float4 ra4 = *reinterpret_cast<const float4*>(&As[k][ty*4]);
            float4 rb4 = *reinterpret_cast<const float4*>(&Bs[k][tx*4]);
            float ra[4] = {ra4.x, ra4.y, ra4.z, ra4.w};
            float rb[4] = {rb4.x, rb4.y, rb4.z, rb4.w};
            #pragma unroll
            for (int i = 0; i < 4; ++i)
                #pragma unroll
                for (int j = 0; j < 4; ++j)
                    acc[i][j] += ra[i] * rb[j];
        }
        __syncthreads();
    }
    if (S == 1) {
        #pragma unroll
        for (int i = 0; i < 4; ++i) {
            int gm = bm + ty*4 + i;
            if (gm >= M) continue;
            #pragma unroll
            for (int j = 0; j < 4; ++j) {
                int gn = bn + tx*4 + j;
                if (gn >= N) continue;
                float v = alpha * acc[i][j];
                if (beta != 0.f) v += beta * C[(size_t)gm*ldc + gn];
                if (relu) v = fmaxf(v, 0.f);
                C[(size_t)gm*ldc + gn] = v;
            }
        }
    } else {
        float* P = Cpart + (size_t)z * M * N;
        #pragma unroll
        for (int i = 0; i < 4; ++i) {
            int gm = bm + ty*4 + i;
            if (gm >= M) continue;
            #pragma unroll
            for (int j = 0; j < 4; ++j) {
                int gn = bn + tx*4 + j;
                if (gn >= N) continue;
                P[(size_t)gm*N + gn] = alpha * acc[i][j];
            }
        }
    }
}

// ---------------------------------------------------------------------------
// 128x128-tile, 8x8/thread f32 GEMM. REQUIRES M%128==0, N%128==0,
// K%S==0, (K/S)%16==0 (dispatcher enforces). No bounds guards.
// ---------------------------------------------------------------------------
template<bool TA, bool TB>
__global__ __launch_bounds__(256)
void gemm128(const float* A, int lda, const float* B, int ldb,
             float* C, int ldc, float* Cpart,
             int M, int N, int K, float alpha, float beta, int relu)
{
    const int S = (int)gridDim.z, z = (int)blockIdx.z;
    const int kchunk = K / S;
    const int k0 = z * kchunk, k1 = k0 + kchunk;
    const int bm = blockIdx.y * 128, bn = blockIdx.x * 128;
    __shared__ float As[16][132];
    __shared__ float Bs[16][132];
    const int tid = threadIdx.x;
    const int tx = tid & 15, ty = tid >> 4;
    float acc[8][8] = {};
    for (int kk = k0; kk < k1; kk += 16) {
        // stage A
        if (!TA) {
            int m = tid >> 1, kb = (tid & 1) * 8;
            const float* src = A + (size_t)(bm + m) * lda + (kk + kb);
            float4 v0 = *(const float4*)src, v1 = *(const float4*)(src + 4);
            float vv[8] = {v0.x,v0.y,v0.z,v0.w,v1.x,v1.y,v1.z,v1.w};
            #pragma unroll
            for (int j = 0; j < 8; ++j) As[kb + j][m] = vv[j];
        } else {
            int kb = tid >> 4, m0 = (tid & 15) * 8;
            const float* src = A + (size_t)(kk + kb) * lda + (bm + m0);
            float4 v0 = *(const float4*)src, v1 = *(const float4*)(src + 4);
            *(float4*)&As[kb][m0] = v0; *(float4*)&As[kb][m0+4] = v1;
        }
        // stage B
        if (!TB) {
            int kb = tid >> 4, n0 = (tid & 15) * 8;
            const float* src = B + (size_t)(kk + kb) * ldb + (bn + n0);
            float4 v0 = *(const float4*)src, v1 = *(const float4*)(src + 4);
            *(float4*)&Bs[kb][n0] = v0; *(float4*)&Bs[kb][n0+4] = v1;
        } else {
            int n = tid >> 1, kb = (tid & 1) * 8;
            const float* src = B + (size_t)(bn + n) * ldb + (kk + kb);
            float4 v0 = *(const float4*)src, v1 = *(const float4*)(src + 4);
            float vv[8] = {v0.x,v0.y,v0.z,v0.w,v1.x,v1.y,v1.z,v1.w};
            #pragma unroll
            for (int j = 0; j < 8; ++j) Bs[kb + j][n] = vv[j];
        }
        __syncthreads();
        #pragma unroll
        for (int k = 0; k < 16; ++k) {
            float4 a0 = *(const float4*)&As[k][ty*8];
            float4 a1 = *(const float4*)&As[k][ty*8+4];
            float4 b0 = *(const float4*)&Bs[k][tx*8];
            float4 b1 = *(const float4*)&Bs[k][tx*8+4];
            float av[8] = {a0.x,a0.y,a0.z,a0.w,a1.x,a1.y,a1.z,a1.w};
            float bv[8] = {b0.x,b0.y,b0.z,b0.w,b1.x,b1.y,b1.z,b1.w};
            #pragma unroll
            for (int i = 0; i < 8; ++i)
                #pragma unroll
                for (int j = 0; j < 8; ++j)
                    acc[i][j] += av[i] * bv[j];
        }
        __syncthreads();
    }
    if (S == 1) {
        #pragma unroll
        for (int i = 0; i < 8; ++i) {
            int gm = bm + ty*8 + i;
            float* cp = C + (size_t)gm*ldc + bn + tx*8;
            float vv[8];
            #pragma unroll
            for (int j = 0; j < 8; ++j) {
                float v = alpha * acc[i][j];
                if (beta != 0.f) v += beta * cp[j];
                if (relu) v = fmaxf(v, 0.f);
                vv[j] = v;
            }
            *(float4*)cp     = make_float4(vv[0],vv[1],vv[2],vv[3]);
            *(float4*)(cp+4) = make_float4(vv[4],vv[5],vv[6],vv[7]);
        }
    } else {
        float* P = Cpart + (size_t)z * M * N;
        #pragma unroll
        for (int i = 0; i < 8; ++i) {
            int gm = bm + ty*8 + i;
            float* pp = P + (size_t)gm*N + bn + tx*8;
            *(float4*)pp     = make_float4(alpha*acc[i][0],alpha*acc[i][1],alpha*acc[i][2],alpha*acc[i][3]);
            *(float4*)(pp+4) = make_float4(alpha*acc[i][4],alpha*acc[i][5],alpha*acc[i][6],alpha*acc[i][7]);
        }
    }
}

// reduce split-K partials; optionally copy rows [r0, r0+64) into ab (A-block stash)
__global__ void reduce_parts(const float* Cpart, float* C, int M, int N, int ldc,
                             int S, float beta, int relu, float* ab, int r0)
{
    int total = M * N;
    for (int idx = blockIdx.x*256 + threadIdx.x; idx < total; idx += gridDim.x*256) {
        float s = 0.f;
        for (int z = 0; z < S; ++z) s += Cpart[(size_t)z*total + idx];
        int mm = idx / N, nn = idx % N;
        float v = s;
        if (beta != 0.f) v += beta * C[(size_t)mm*ldc + nn];
        if (relu) v = fmaxf(v, 0.f);
        C[(size_t)mm*ldc + nn] = v;
        if (ab && mm >= r0) ab[(size_t)(mm - r0)*N + nn] = v;
    }
}

// fallback A-block copy when S==1 (no reduce pass ran)
__global__ void copy_rows64(const float* C, int ldc, float* ab, int r0, int N) {
    int idx = blockIdx.x*256 + threadIdx.x;
    if (idx < 64*N) {
        int r = idx / N, nn = idx % N;
        ab[(size_t)r*N + nn] = C[(size_t)(r0 + r)*ldc + nn];
    }
}

// ---------------------------------------------------------------------------
// Small utility kernels
// ---------------------------------------------------------------------------
__global__ void row_deg(const float* H, float* dv) {
    int row = blockIdx.x*4 + (threadIdx.x >> 6);
    int lane = threadIdx.x & 63;
    if (row >= 2048) return;
    float s = 0.f;
    for (int e = lane; e < 1024; e += 64) s += H[(size_t)row*1024 + e];
    for (int o = 32; o; o >>= 1) s += __shfl_down(s, o, 64);
    if (lane == 0) dv[row] = s;
}

// column dot: part[z][e] = sum_{n in chunk z} H[n][e] * (w ? w[n] : 1)
__global__ void coldot_part(const float* H, const float* w, float* part) {
    int e = blockIdx.x*256 + threadIdx.x;   // gridDim.x = 4
    int zc = blockIdx.y;                    // 8 chunks over nodes
    float s = 0.f;
    if (w) {
        for (int n = zc*256; n < zc*256 + 256; ++n) s += H[(size_t)n*1024 + e] * w[n];
    } else {
        for (int n = zc*256; n < zc*256 + 256; ++n) s += H[(size_t)n*1024 + e];
    }
    part[(size_t)zc*1024 + e] = s;
}
__global__ void coldot_fin(const float* part, float* outp) {
    int e = blockIdx.x*256 + threadIdx.x;
    float s = 0.f;
    for (int z = 0; z < 8; ++z) s += part[(size_t)z*1024 + e];
    outp[e] = s;
}

__global__ void dot_partial(const float* a, const float* b, int n, float* partials) {
    __shared__ float red[256];
    int tid = threadIdx.x;
    float s = 0.f;
    for (int i = blockIdx.x*256 + tid; i < n; i += gridDim.x*256) s += a[i]*b[i];
    red[tid] = s; __syncthreads();
    for (int st = 128; st; st >>= 1) { if (tid < st) red[tid] += red[tid+st]; __syncthreads(); }
    if (tid == 0) partials[blockIdx.x] = red[0];
}
__global__ void finalize_sum(const float* partials, int n, float* outp) {
    __shared__ float red[256];
    int tid = threadIdx.x;
    red[tid] = (tid < n) ? partials[tid] : 0.f;
    __syncthreads();
    for (int st = 128; st; st >>= 1) { if (tid < st) red[tid] += red[tid+st]; __syncthreads(); }
    if (tid == 0) *outp = red[0];
}

// y = h / sqrt(dv+eps); srow = rowwise sum(y^2)
__global__ void yscale(const float* h, int F, const float* dv, float* y, float* srow) {
    int row = blockIdx.x*4 + (threadIdx.x >> 6);
    int lane = threadIdx.x & 63;
    if (row >= 2048) return;
    float rs = 1.0f / sqrtf(dv[row] + 1e-10f);
    float ss = 0.f;
    for (int f = lane; f < F; f += 64) {
        float t = h[(size_t)row*F + f] * rs;
        y[(size_t)row*F + f] = t;
        ss += t*t;
    }
    for (int o = 32; o; o >>= 1) ss += __shfl_down(ss, o, 64);
    if (lane == 0) srow[row] = ss;
}

// per-edge: (d_e*q_e - ||m_e||^2)/(d_e+eps); q_e summed from qpart slices
__global__ void edge_energy(const float* m, int F, const float* de, const float* qpart,
                            float* partials) {
    int wave = threadIdx.x >> 6, lane = threadIdx.x & 63;
    __shared__ float acc4[4];
    float acc = 0.f;
    for (int t = 0; t < 16; ++t) {
        int e = blockIdx.x*64 + wave*16 + t;
        float me2 = 0.f;
        for (int f = lane; f < F; f += 64) { float v = m[(size_t)e*F + f]; me2 += v*v; }
        for (int o = 32; o; o >>= 1) me2 += __shfl_down(me2, o, 64);
        if (lane == 0) {
            float q = 0.f;
            for (int z = 0; z < 8; ++z) q += qpart[(size_t)z*1024 + e];
            acc += (de[e]*q - me2) / (de[e] + 1e-10f);
        }
    }
    if (lane == 0) acc4[wave] = acc;
    __syncthreads();
    if (threadIdx.x == 0) partials[blockIdx.x] = acc4[0]+acc4[1]+acc4[2]+acc4[3];
}

// log_softmax over axis=1 (the 2048 nodes), per class column
__global__ void logsoftmax(const float* xf, float* outp) {
    __shared__ float red[256];
    int c = blockIdx.x, tid = threadIdx.x;
    float mx = -3.0e38f;
    for (int n = tid; n < 2048; n += 256) mx = fmaxf(mx, xf[(size_t)n*40 + c]);
    red[tid] = mx; __syncthreads();
    for (int st = 128; st; st >>= 1) { if (tid < st) red[tid] = fmaxf(red[tid], red[tid+st]); __syncthreads(); }
    mx = red[0]; __syncthreads();
    float s = 0.f;
    for (int n = tid; n < 2048; n += 256) s += expf(xf[(size_t)n*40 + c] - mx);
    red[tid] = s; __syncthreads();
    for (int st = 128; st; st >>= 1) { if (tid < st) red[tid] += red[tid+st]; __syncthreads(); }
    float lse = mx + logf(red[0]);
    for (int n = tid; n < 2048; n += 256) outp[(size_t)n*40 + c] = xf[(size_t)n*40 + c] - lse;
}

// ---------------------------------------------------------------------------
// Block-Lanczos support
// ---------------------------------------------------------------------------
__global__ void init_q0(float* Q) {
    int idx = blockIdx.x*256 + threadIdx.x;
    if (idx < 2048*64) {
        int n = idx >> 6, c = idx & 63;
        Q[(size_t)n*2048 + c] = (n == c) ? 1.f : 0.f;
    }
}

// Cholesky of 64x64 G = sum of S split-K partials (upper R), Rinv = R^{-1}.
// mode0: Bout=R. mode1: Bout = R*Bout_old.
__global__ __launch_bounds__(256)
void cholinv(const float* Gp, int S, float* Rinv, float* Bout, int mode) {
    __shared__ float R[64][65];
    __shared__ float Xs[64][65];
    int tid = threadIdx.x;
    for (int idx = tid; idx < 4096; idx += 256) {
        float g = 0.f;
        for (int z = 0; z < S; ++z) g += Gp[(size_t)z*4096 + idx];
        R[idx>>6][idx&63] = g;
    }
    __syncthreads();
    for (int k = 0; k < 64; ++k) {
        if (tid == 0) R[k][k] = sqrtf(fmaxf(R[k][k], 1e-20f));
        __syncthreads();
        float rkk = R[k][k];
        for (int j = k + 1 + tid; j < 64; j += 256) R[k][j] /= rkk;
        __syncthreads();
        for (int idx = tid; idx < 4096; idx += 256) {
            int i = idx>>6, j = idx&63;
            if (i > k && j >= i) R[i][j] -= R[k][i]*R[k][j];
        }
        __syncthreads();
    }
    for (int idx = tid; idx < 4096; idx += 256) Xs[idx>>6][idx&63] = 0.f;
    __syncthreads();
    if (tid < 64) {
        int j = tid;
        for (int i = j; i >= 0; --i) {
            float s = (i == j) ? 1.f : 0.f;
            for (int k2 = i + 1; k2 <= j; ++k2) s -= R[i][k2]*Xs[k2][j];
            Xs[i][j] = s / R[i][i];
        }
    }
    __syncthreads();
    for (int idx = tid; idx < 4096; idx += 256) Rinv[idx] = Xs[idx>>6][idx&63];
    __syncthreads();
    if (mode == 0) {
        for (int idx = tid; idx < 4096; idx += 256) {
            int i = idx>>6, j = idx&63;
            Bout[idx] = (j >= i) ? R[i][j] : 0.f;
        }
    } else {
        for (int idx = tid; idx < 4096; idx += 256) Xs[idx>>6][idx&63] = Bout[idx];
        __syncthreads();
        for (int idx = tid; idx < 4096; idx += 256) {
            int i = idx>>6, j = idx&63;
            float s = 0.f;
            if (j >= i) for (int k2 = i; k2 <= j; ++k2) s += R[i][k2]*Xs[k2][j];
            Bout[idx] = s;
        }
    }
}

// band[c*65+r] = T[c+r, c], r=0..64 (lower band, bandwidth 64)
__global__ void assemble_band(const float* Ab, const float* Bb, float* band) {
    int idx = blockIdx.x*256 + threadIdx.x;
    if (idx >= 2048*65) return;
    int c = idx / 65, r = idx % 65;
    int row = c + r;
    float v = 0.f;
    if (row < 2048) {
        int j = c >> 6, q = c & 63, rr = q + r;
        if (rr <= 63) {
            const float* A = Ab + (size_t)j*4096;
            v = 0.5f*(A[rr*64 + q] + A[q*64 + rr]);
        } else if (j < 31) {
            int p = rr - 64;
            v = Bb[(size_t)j*4096 + p*64 + q];
        }
    }
    band[idx] = v;
}

// Sturm count via band LDL^T in f64, one workgroup per shift. grid = 256 shifts.
__global__ __launch_bounds__(256)
void band_count(const float* band, const double* shifts, int* counts) {
    __shared__ double win[65][66];
    __shared__ double lvec[65];
    __shared__ int cnt;
    int tid = threadIdx.x;
    double sigma = shifts[blockIdx.x];
    if (tid == 0) cnt = 0;
    for (int idx = tid; idx < 65*65; idx += 256) {
        int c = idx / 65, r = idx % 65;
        win[c][r] = (double)band[c*65 + r] - (r == 0 ? sigma : 0.0);
    }
    __syncthreads();
    for (int c = 0; c < 2048; ++c) {
        int cs = c % 65;
        double d = win[cs][0];
        if (fabs(d) < 1e-100) d = (d < 0 ? -1e-100 : 1e-100);
        if (tid == 0 && d < 0) cnt++;
        if (tid >= 1 && tid <= 64) lvec[tid] = win[cs][tid] / d;
        __syncthreads();
        for (int idx = tid; idx < 4096; idx += 256) {
            int i = (idx >> 6) + 1, j = (idx & 63) + 1;
            if (j >= i) win[(cs + i) % 65][j - i] -= lvec[i] * win[cs][j];
        }
        __syncthreads();
        int cn = c + 65;
        if (cn < 2048) {
            for (int r = tid; r <= 64; r += 256)
                win[cs][r] = (double)band[cn*65 + r] - (r == 0 ? sigma : 0.0);
        }
    }
    __syncthreads();
    if (tid == 0) counts[blockIdx.x] = cnt;
}

#define NSHIFT 256
// Bisection driver. mode0: init log-spaced shifts. mode1: bracket + linear refine.
// mode3: final write of gap.
__global__ void bisect(double* shifts, const int* counts, double* st, float* gap_out, int mode) {
    if (threadIdx.x != 0) return;
    if (mode == 0) {
        shifts[0] = 1e-10;
        double l0 = log(1e-6), l1 = log(0.5);
        for (int i = 1; i < NSHIFT; ++i) shifts[i] = exp(l0 + (l1 - l0)*(i - 1)/(double)(NSHIFT - 2));
        return;
    }
    if (mode == 1) {
        int n0 = counts[0];
        double lo = shifts[NSHIFT-1], hi = 1.5;
        for (int i = 1; i < NSHIFT; ++i) if (counts[i] > n0) { lo = shifts[i-1]; hi = shifts[i]; break; }
        st[0] = lo; st[1] = hi; st[2] = (double)n0;
        for (int i = 0; i < NSHIFT; ++i) shifts[i] = lo + (hi - lo)*(i + 1)/(double)(NSHIFT + 1);
        return;
    }
    int n0 = (int)st[2];
    double lo = st[0], hi = st[1];
    double nlo = shifts[NSHIFT-1], nhi = hi;
    for (int i = 0; i < NSHIFT; ++i) if (counts[i] > n0) { nhi = shifts[i]; nlo = (i == 0) ? lo : shifts[i-1]; break; }
    *gap_out = (float)(0.5*(nlo + nhi));
}

// Lanczos (32 steps) on Gram matrix -> sigma_max = sqrt(lambda_max)
__global__ __launch_bounds__(256)
void snorm_lanczos(const float* Gall, const float* G40, float* outp) {
    int w = blockIdx.x, tid = threadIdx.x;
    int n = (w < 9) ? 512 : 40;
    const float* G = (w < 9) ? (Gall + (size_t)w*512*512) : G40;
    __shared__ float v[512], vp[512], wv[512], red[256];
    __shared__ float al[32], be[32];
    float inv0 = 1.f / sqrtf((float)n);
    for (int i = tid; i < n; i += 256) { v[i] = inv0; vp[i] = 0.f; }
    __syncthreads();
    float beta_prev = 0.f;
    for (int s = 0; s < 32; ++s) {
        for (int r = tid; r < n; r += 256) {
            const float* row = G + (size_t)r*n;
            float sum = 0.f;
            for (int k2 = 0; k2 < n; ++k2) sum += row[k2]*v[k2];
            wv[r] = sum;
        }
        __syncthreads();
        float p = 0.f;
        for (int i = tid; i < n; i += 256) p += v[i]*wv[i];
        red[tid] = p; __syncthreads();
        for (int st = 128; st; st >>= 1) { if (tid < st) red[tid] += red[tid+st]; __syncthreads(); }
        float alpha = red[0]; __syncthreads();
        for (int i = tid; i < n; i += 256) wv[i] -= alpha*v[i] + beta_prev*vp[i];
        __syncthreads();
        p = 0.f;
        for (int i = tid; i < n; i += 256) p += wv[i]*wv[i];
        red[tid] = p; __syncthreads();
        for (int st = 128; st; st >>= 1) { if (tid < st) red[tid] += red[tid+st]; __syncthreads(); }
        float beta = sqrtf(fmaxf(red[0], 0.f)); __syncthreads();
        if (tid == 0) { al[s] = alpha; be[s] = beta; }
        float ib = 1.f / fmaxf(beta, 1e-20f);
        for (int i = tid; i < n; i += 256) { float t = v[i]; vp[i] = t; v[i] = wv[i]*ib; }
        beta_prev = beta;
        __syncthreads();
    }
    if (tid == 0) {
        float hi = 0.f;
        for (int s = 0; s < 32; ++s) {
            float g2 = al[s] + be[s] + (s ? be[s-1] : 0.f);
            hi = fmaxf(hi, g2);
        }
        float lo = 0.f;
        for (int it = 0; it < 48; ++it) {
            float mid = 0.5f*(lo + hi);
            float d = al[0] - mid; int c2 = (d < 0.f);
            for (int s = 1; s < 32; ++s) {
                float dp = d;
                if (fabsf(dp) < 1e-25f) dp = (dp < 0.f) ? -1e-25f : 1e-25f;
                d = (al[s] - mid) - be[s-1]*be[s-1]/dp;
                c2 += (d < 0.f);
            }
            if (c2 == 32) hi = mid; else lo = mid;
        }
        outp[w] = sqrtf(fmaxf(0.5f*(lo + hi), 0.f));
    }
}

// ---------------------------------------------------------------------------
// Host driver
// ---------------------------------------------------------------------------
static int gemm(hipStream_t st, int ta, int tb, int M, int N, int K,
                const float* A, int lda, const float* B, int ldb,
                float* C, int ldc, float alpha, float beta, int relu,
                float* Cpart, int cap, int Swant, int do_reduce,
                float* ab, int r0)
{
    int S = Swant;
    if (S > 1) {
        long long need = (long long)M * N;
        int smax = (int)((long long)cap / need);
        if (smax < 1) smax = 1;
        if (S > smax) S = smax;
    }
    bool big = (M % 128 == 0) && (N % 128 == 0) && (K % 16 == 0) &&
               (K % S == 0) && (((K / S) % 16) == 0);
    if (big) {
        dim3 grid((unsigned)(N/128), (unsigned)(M/128), (unsigned)S);
        if (!ta && !tb)      gemm128<false,false><<<grid,256,0,st>>>(A,lda,B,ldb,C,ldc,Cpart,M,N,K,alpha,beta,relu);
        else if (!ta && tb)  gemm128<false,true ><<<grid,256,0,st>>>(A,lda,B,ldb,C,ldc,Cpart,M,N,K,alpha,beta,relu);
        else if (ta && !tb)  gemm128<true ,false><<<grid,256,0,st>>>(A,lda,B,ldb,C,ldc,Cpart,M,N,K,alpha,beta,relu);
        else                 gemm128<true ,true ><<<grid,256,0,st>>>(A,lda,B,ldb,C,ldc,Cpart,M,N,K,alpha,beta,relu);
    } else {
        dim3 grid((unsigned)((N + 63)/64), (unsigned)((M + 63)/64), (unsigned)S);
        if (!ta && !tb)      gemm_f32<false,false><<<grid,256,0,st>>>(A,lda,B,ldb,C,ldc,Cpart,M,N,K,alpha,beta,relu);
        else if (!ta && tb)  gemm_f32<false,true ><<<grid,256,0,st>>>(A,lda,B,ldb,C,ldc,Cpart,M,N,K,alpha,beta,relu);
        else if (ta && !tb)  gemm_f32<true ,false><<<grid,256,0,st>>>(A,lda,B,ldb,C,ldc,Cpart,M,N,K,alpha,beta,relu);
        else                 gemm_f32<true ,true ><<<grid,256,0,st>>>(A,lda,B,ldb,C,ldc,Cpart,M,N,K,alpha,beta,relu);
    }
    if (S > 1 && do_reduce) {
        int total = M * N;
        int g = (total + 255)/256; if (g > 2048) g = 2048;
        reduce_parts<<<g,256,0,st>>>(Cpart, C, M, N, ldc, S, beta, relu, ab, r0);
    } else if (ab) {
        copy_rows64<<<(64*N + 255)/256,256,0,st>>>(C, ldc, ab, r0, N);
    }
    return S;
}

extern "C" void kernel_launch(void* const* d_in, const int* in_sizes, int n_in,
                              void* d_out, int out_size, void* d_ws, size_t ws_size,
                              hipStream_t stream)
{
    (void)in_sizes; (void)n_in; (void)out_size;
    const float* X  = (const float*)d_in[0];   // [1,2048,512]
    const float* Lm = (const float*)d_in[1];   // [1,2048,2048]
    const float* H  = (const float*)d_in[2];   // [2048,1024]
    const float* Wf = (const float*)d_in[3];   // [512,512]
    const float* Wm = (const float*)d_in[4];   // [8,512,512]
    const float* Wl = (const float*)d_in[5];   // [40,512]
    float* out = (float*)d_out;

    float* ws = (float*)d_ws;
    size_t off = 0;
    auto alloc = [&](size_t n) { float* p = ws + off; off += (n + 255) & ~(size_t)255; return p; };
    float* hA    = alloc((size_t)2048*512);
    float* hB    = alloc((size_t)2048*512);
    float* u     = alloc((size_t)2048*512);
    float* y     = alloc((size_t)2048*512);
    float* mE    = alloc((size_t)1024*512);
    float* Qall  = alloc((size_t)2048*2048);      // Lanczos basis; reused for snorm Grams
    float* Z     = alloc((size_t)2048*64);
    float* Creo  = alloc((size_t)2048*64);
    float* Rinv  = alloc(64*64);
    float* Ab    = alloc((size_t)32*64*64);
    float* Bb    = alloc((size_t)32*64*64);
    float* band  = alloc((size_t)2048*65);
    float* G40   = alloc(40*40);
    float* dv    = alloc(2048);
    float* de    = alloc(1024);
    float* srow  = alloc(2048);
    float* qpart = alloc(8*1024);
    float* partials = alloc(256);
    double* shifts  = (double*)alloc(2*NSHIFT);
    double* bstate  = (double*)alloc(8);
    int* counts     = (int*)alloc(NSHIFT);
    float* Cpart = alloc((size_t)1024*1024);      // allocated LAST: may extend
    // extend Cpart to 4M floats if workspace provably fits
    int cap = 1024*1024;
    if (ws_size >= (off + (size_t)3*1024*1024) * sizeof(float)) cap = 4*1024*1024;
    float* sG = Qall;  // reuse after band assembly

    // degrees
    row_deg<<<512,256,0,stream>>>(H, dv);
    coldot_part<<<dim3(4,8),256,0,stream>>>(H, nullptr, qpart);
    coldot_fin<<<4,256,0,stream>>>(qpart, de);

    // u0 = L x
    gemm(stream, 0,0, 2048,512,2048, Lm,2048, X,512, u,512, 1.f,0.f,0, Cpart,cap,4,1, nullptr,0);

    // 10 layers
    for (int k = 0; k < 10; ++k) {
        const int Fo = (k < 9) ? 512 : 40;
        const float* W = (k == 0) ? Wf : ((k < 9) ? (Wm + (size_t)(k-1)*512*512) : Wl);
        float* h = (k & 1) ? hB : hA;
        // h = relu(u W^T)
        gemm(stream, 0,1, 2048,Fo,512, u,512, W,512, h,Fo, 1.f,0.f,1, Cpart,cap,(Fo==512)?4:8,1, nullptr,0);
        // u = L h   (serves energy AND next layer)
        gemm(stream, 0,0, 2048,Fo,2048, Lm,2048, h,Fo, u,Fo, 1.f,0.f,0, Cpart,cap,(Fo==512)?4:8,1, nullptr,0);
        // energies[k] = <h, u>
        dot_partial<<<256,256,0,stream>>>(h, u, 2048*Fo, partials);
        finalize_sum<<<1,256,0,stream>>>(partials, 256, out + 81920 + k);
        // expanded energy
        yscale<<<512,256,0,stream>>>(h, Fo, dv, y, srow);
        coldot_part<<<dim3(4,8),256,0,stream>>>(H, srow, qpart);
        gemm(stream, 1,0, 1024,Fo,2048, H,1024, y,Fo, mE,Fo, 1.f,0.f,0, Cpart,cap,8,1, nullptr,0);
        edge_energy<<<16,256,0,stream>>>(mE, Fo, de, qpart, partials);
        finalize_sum<<<1,256,0,stream>>>(partials, 16, out + 81930 + k);
    }
    // log_softmax over nodes; final h lives in hB (k=9 odd)
    logsoftmax<<<40,256,0,stream>>>(hB, out);

    // ---- block Lanczos -> band-64 similar matrix ----
    init_q0<<<512,256,0,stream>>>(Qall);
    for (int s = 0; s < 32; ++s) {
        // Z = L * Q_s
        gemm(stream, 0,0, 2048,64,2048, Lm,2048, Qall + 64*s,2048, Z,64, 1.f,0.f,0, Cpart,cap,8,1, nullptr,0);
        // Creo = Qall(:,0..64(s+1))^T * Z ; last 64 rows = A_s (stashed via reduce)
        gemm(stream, 1,0, 64*(s+1),64,2048, Qall,2048, Z,64, Creo,64, 1.f,0.f,0, Cpart,cap,8,1, Ab + (size_t)s*4096, 64*s);
        // Z -= Qall * Creo  (full one-pass reorthogonalization)
        gemm(stream, 0,0, 2048,64,64*(s+1), Qall,2048, Creo,64, Z,64, -1.f,1.f,0, Cpart,cap,8,1, nullptr,0);
        if (s < 31) {
            // CholQR pass 1 (Gram partials consumed directly by cholinv)
            int Sg = gemm(stream, 1,0, 64,64,2048, Z,64, Z,64, Rinv,64, 1.f,0.f,0, Cpart,cap,16,0, nullptr,0);
            cholinv<<<1,256,0,stream>>>(Cpart, Sg, Rinv, Bb + (size_t)s*4096, 0);
            gemm(stream, 0,0, 2048,64,64, Z,64, Rinv,64, Qall + 64*(s+1),2048, 1.f,0.f,0, Cpart,cap,1,1, nullptr,0);
            // CholQR pass 2 (in-place refresh of block s+1), B_s = R2*R1
            Sg = gemm(stream, 1,0, 64,64,2048, Qall + 64*(s+1),2048, Qall + 64*(s+1),2048, Rinv,64, 1.f,0.f,0, Cpart,cap,16,0, nullptr,0);
            cholinv<<<1,256,0,stream>>>(Cpart, Sg, Rinv, Bb + (size_t)s*4096, 1);
            gemm(stream, 0,0, 2048,64,64, Qall + 64*(s+1),2048, Rinv,64, Qall + 64*(s+1),2048, 1.f,0.f,0, Cpart,cap,1,1, nullptr,0);
        }
    }
    assemble_band<<<520,256,0,stream>>>(Ab, Bb, band);
    // inertia bisection for smallest eigenvalue > 1e-10 (2 rounds x 256 shifts)
    bisect<<<1,64,0,stream>>>(shifts, counts, bstate, out + 81950, 0);
    band_count<<<NSHIFT,256,0,stream>>>(band, shifts, counts);
    bisect<<<1,64,0,stream>>>(shifts, counts, bstate, out + 81950, 1);
    band_count<<<NSHIFT,256,0,stream>>>(band, shifts, counts);
    bisect<<<1,64,0,stream>>>(shifts, counts, bstate, out + 81950, 3);

    // ---- spectral norms ----
    for (int i = 0; i < 9; ++i) {
        const float* W = (i == 0) ? Wf : (Wm + (size_t)(i-1)*512*512);
        gemm(stream, 1,0, 512,512,512, W,512, W,512, sG + (size_t)i*512*512,512, 1.f,0.f,0, Cpart,cap,1,1, nullptr,0);
    }
    gemm(stream, 0,1, 40,40,512, Wl,512, Wl,512, G40,40, 1.f,0.f,0, Cpart,cap,8,1, nullptr,0);
    snorm_lanczos<<<10,256,0,stream>>>(sG, G40, out + 81940);
}